// Round 1
// baseline (198.899 us; speedup 1.0000x reference)
//
#include <hip/hip_runtime.h>
#include <stdint.h>

#define HH 224
#define WW 224
#define NSEAM 7
#define BWIDTH 5
#define NP 11
#define BB 256
#define KK 64

// ---------------------------------------------------------------------------
// Kernel 1: seam DP. One thread per (batch, dir, seam): 256*14 = 3584 threads.
// Replicates JAX reference exactly:
//   C[r][j] = -g at band position j; cost = min(prev[j-1],prev[j],prev[j+1]) + C
//   candidate order [clip(j-1), j, clip(j+1)], first-min tie-break,
//   final argmin first-min, backtrack through stored 2-bit choices.
// ---------------------------------------------------------------------------
__global__ __launch_bounds__(64) void dp_kernel(const float* __restrict__ g,
                                                int* __restrict__ paths) {
    // choices per local thread, rows 1..223; stride 225 dwords -> conflict-free
    __shared__ uint32_t ch[64][225];
    int t = blockIdx.x * 64 + threadIdx.x;
    int b = t / 14;
    int s = t % 14;          // s = dir*7 + p
    int dir = s / 7;
    int p = s % 7;
    const float* gb = g + (size_t)b * HH * WW;
    int c0 = 28 * (p + 1) - BWIDTH;          // band base (col for dir0, row for dir1)
    int rs = (dir == 0) ? WW : 1;            // step-axis stride
    int cs = (dir == 0) ? 1 : WW;            // band-axis stride
    const float* gbase = gb + (size_t)c0 * cs;

    float cost[NP];
#pragma unroll
    for (int j = 0; j < NP; ++j) cost[j] = -gbase[j * cs];

    for (int r = 1; r < HH; ++r) {
        float prev[NP];
#pragma unroll
        for (int j = 0; j < NP; ++j) prev[j] = cost[j];
        uint32_t code = 0;
        const float* grow = gbase + (size_t)r * rs;
#pragma unroll
        for (int j = 0; j < NP; ++j) {
            int jm = (j == 0) ? 0 : j - 1;
            int jp = (j == NP - 1) ? NP - 1 : j + 1;
            // candidate order matches reference: [jm, j, jp], strict < keeps first min
            float best = prev[jm]; int bsel = jm;
            if (prev[j]  < best) { best = prev[j];  bsel = j;  }
            if (prev[jp] < best) { best = prev[jp]; bsel = jp; }
            cost[j] = best - grow[j * cs];   // == best + (-g), exact IEEE identity
            code |= (uint32_t)(bsel - j + 1) << (2 * j);
        }
        ch[threadIdx.x][r] = code;
    }

    // final argmin, first occurrence
    float bv = cost[0]; int pos = 0;
#pragma unroll
    for (int j = 1; j < NP; ++j) if (cost[j] < bv) { bv = cost[j]; pos = j; }

    int* op = paths + (size_t)t * HH;        // layout [B][14][224]
    op[HH - 1] = c0 + pos;
    for (int r = HH - 1; r >= 1; --r) {
        uint32_t code = ch[threadIdx.x][r];
        int sel = (int)((code >> (2 * pos)) & 3u);
        pos += sel - 1;
        op[r - 1] = c0 + pos;
    }
}

// ---------------------------------------------------------------------------
// Kernel 2: labels + centroids. One block per image.
// lab(y,x) = #{p: vcol[p][y] <= x} + 8 * #{p: hrow[p][x] <= y}
// Centroid sums via single packed u64 LDS atomic per pixel:
//   bits [42..63]=count, [21..41]=sum_y, [0..20]=sum_x.
// Region bounds (<=38x38 px, sums <= ~322K < 2^21) => no field overflow,
// and all sums < 2^22 are exact in f32 => division bitwise matches JAX.
// ---------------------------------------------------------------------------
__global__ __launch_bounds__(256) void label_kernel(const int* __restrict__ paths,
                                                    float* __restrict__ out) {
    int b = blockIdx.x;
    __shared__ int vp[NSEAM][HH];   // [seam][row]  -> column
    __shared__ int hp[NSEAM][WW];   // [seam][col]  -> row
    __shared__ unsigned long long acc[KK];

    const int* pb = paths + (size_t)b * 14 * HH;
    for (int i = threadIdx.x; i < NSEAM * HH; i += blockDim.x) {
        vp[i / HH][i % HH] = pb[i];
        hp[i / WW][i % WW] = pb[NSEAM * HH + i];
    }
    if (threadIdx.x < KK) acc[threadIdx.x] = 0ull;
    __syncthreads();

    float* mb = out + (size_t)BB * KK * 2 + (size_t)b * HH * WW;
    for (int i = threadIdx.x; i < HH * WW; i += blockDim.x) {
        int y = i / WW, x = i - y * WW;
        int vl = 0, hl = 0;
#pragma unroll
        for (int q = 0; q < NSEAM; ++q) {
            vl += (vp[q][y] <= x) ? 1 : 0;
            hl += (hp[q][x] <= y) ? 1 : 0;
        }
        int lab = vl + 8 * hl;
        mb[i] = (float)lab;
        unsigned long long v = (1ull << 42) |
                               ((unsigned long long)(unsigned)y << 21) |
                               (unsigned long long)(unsigned)x;
        atomicAdd(&acc[lab], v);
    }
    __syncthreads();

    if (threadIdx.x < KK) {
        unsigned long long sv = acc[threadIdx.x];
        float cnt = (float)(unsigned)(sv >> 42);
        float sy  = (float)(unsigned)((sv >> 21) & 0x1FFFFFu);
        float sx  = (float)(unsigned)(sv & 0x1FFFFFu);
        float* cb = out + (size_t)b * KK * 2;
        cb[threadIdx.x * 2 + 0] = sy / cnt;
        cb[threadIdx.x * 2 + 1] = sx / cnt;
    }
}

extern "C" void kernel_launch(void* const* d_in, const int* in_sizes, int n_in,
                              void* d_out, int out_size, void* d_ws, size_t ws_size,
                              hipStream_t stream) {
    // d_in[0] = x (unused by reference), d_in[1] = grad_map (B,H,W) f32
    const float* g = (const float*)d_in[1];
    float* out = (float*)d_out;
    int* paths = (int*)d_ws;    // needs 256*14*224*4 = 3,211,264 bytes

    dp_kernel<<<(BB * 14) / 64, 64, 0, stream>>>(g, paths);
    label_kernel<<<BB, 256, 0, stream>>>(paths, out);
}

// Round 2
// 87.365 us; speedup vs baseline: 2.2767x; 2.2767x over previous
//
#include <hip/hip_runtime.h>
#include <stdint.h>

#define HH 224
#define WW 224
#define NSEAM 7
#define BWIDTH 5
#define NP 11
#define BB 256
#define KK 64

// DPP helpers (ctrl must be literal): row_shr:1=0x111 (dst[i]=src[i-1]),
// row_shl:1=0x101 (dst[i]=src[i+1]), row_ror:N=0x120+N. Rows = 16 lanes.
#define DPPF_OLD(old, src, ctrl) \
    __int_as_float(__builtin_amdgcn_update_dpp(__float_as_int(old), __float_as_int(src), ctrl, 0xF, 0xF, false))
#define DPPF_Z(src, ctrl) \
    __int_as_float(__builtin_amdgcn_update_dpp(0, __float_as_int(src), ctrl, 0xF, 0xF, true))
#define DPPI_Z(src, ctrl) \
    __builtin_amdgcn_update_dpp(0, (int)(src), ctrl, 0xF, 0xF, true)

// ---------------------------------------------------------------------------
// Kernel 1: seam DP, 16 lanes per DP (lane j = band position j, 11 active).
// 3584 DPs -> 224 blocks x 256 threads (16 groups/block).
// Exact reference semantics: candidates [jm, j, jp], strict-< first-min,
// cost = best - g (same IEEE sequence), final argmin first-min, backtrack.
// ---------------------------------------------------------------------------
__global__ __launch_bounds__(256) void dp_kernel(const float* __restrict__ g,
                                                 int* __restrict__ paths) {
    __shared__ uint32_t ch[16][226];   // packed 2-bit sels, 11 lanes per word
    __shared__ int      pth[16][226];  // backtracked path positions

    const int j   = threadIdx.x & 15;
    const int grp = threadIdx.x >> 4;
    const int gid = blockIdx.x * 16 + grp;      // (b, dir, seam)
    const int b   = gid / 14;
    const int s   = gid % 14;
    const int dir = s / 7;
    const int p   = s % 7;
    const int band0 = 28 * (p + 1) - BWIDTH;
    const int rs = (dir == 0) ? WW : 1;         // step-axis stride
    const int cs = (dir == 0) ? 1 : WW;         // band-axis stride
    const int jc = (j > 10) ? 10 : j;           // clamp junk lanes' loads
    const float* gptr = g + (size_t)b * HH * WW + (size_t)(band0 + jc) * cs;

    float ga[16], gb_[16];
    float cost = 0.0f;

#define LOADC(buf, c)                                                       \
    _Pragma("unroll")                                                       \
    for (int rr = 0; rr < 16; ++rr) buf[rr] = gptr[((c) * 16 + rr) * rs];

#define PROCC(buf, c)                                                       \
    _Pragma("unroll")                                                       \
    for (int rr = 0; rr < 16; ++rr) {                                       \
        if (rr == 0 && (c) == 0) {                                          \
            cost = -buf[0];                                                 \
        } else {                                                            \
            float pm  = DPPF_OLD(cost, cost, 0x111); /* prev[j-1], lane0->old=prev[0] */ \
            float ppv = DPPF_OLD(cost, cost, 0x101); /* prev[j+1], lane15->old */        \
            ppv = (j >= 10) ? cost : ppv;            /* clip at j=10 */                  \
            float best = pm; int sel = (j == 0) ? 1 : 0;                    \
            if (cost < best) { best = cost; sel = 1; }                      \
            if (ppv  < best) { best = ppv;  sel = 2; }                      \
            cost = best - buf[rr];                                          \
            uint32_t u = (uint32_t)sel << (2 * j);                          \
            u |= (uint32_t)DPPI_Z(u, 0x128);                                \
            u |= (uint32_t)DPPI_Z(u, 0x124);                                \
            u |= (uint32_t)DPPI_Z(u, 0x122);                                \
            u |= (uint32_t)DPPI_Z(u, 0x121);                                \
            if (j == 0) ch[grp][(c) * 16 + rr] = u;                         \
        }                                                                   \
    }

    LOADC(ga, 0);
    for (int cc = 0; cc < 7; ++cc) {
        const int ce = 2 * cc, co = 2 * cc + 1;
        LOADC(gb_, co);
        PROCC(ga, ce);
        if (cc < 6) LOADC(ga, co + 1);
        PROCC(gb_, co);
    }

    // final argmin across 11 lanes, first-min tie-break == lexicographic min
    float rc = (j <= 10) ? cost : INFINITY;
    int   ri = (j <= 10) ? j : 15;
#define REDSTEP(ctrl)                                                        \
    {                                                                        \
        float oc = DPPF_Z(rc, ctrl);                                         \
        int   oi = DPPI_Z(ri, ctrl);                                         \
        bool t = (oc < rc) || (oc == rc && oi < ri);                         \
        rc = t ? oc : rc; ri = t ? oi : ri;                                  \
    }
    REDSTEP(0x128) REDSTEP(0x124) REDSTEP(0x122) REDSTEP(0x121)

    int pos = ri;
    if (j == 0) pth[grp][HH - 1] = band0 + pos;

    // backtrack: uniform (broadcast) LDS reads issued ahead; chain is 3 VALU/row
    for (int c = 13; c >= 0; --c) {
        uint32_t w[16];
#pragma unroll
        for (int rr = 0; rr < 16; ++rr) w[rr] = ch[grp][c * 16 + rr];
#pragma unroll
        for (int rr = 15; rr >= 0; --rr) {
            int r = c * 16 + rr;
            if (r >= 1) {
                int sel = (int)((w[rr] >> (2 * pos)) & 3u);
                pos += sel - 1;
                if (j == 0) pth[grp][r - 1] = band0 + pos;
            }
        }
    }

    int* op = paths + (size_t)gid * HH;
#pragma unroll
    for (int c = 0; c < 14; ++c) op[c * 16 + j] = pth[grp][c * 16 + j];

#undef LOADC
#undef PROCC
#undef REDSTEP
}

// ---------------------------------------------------------------------------
// Kernel 2: labels + centroids. One block per image, one thread per column.
// Walking down a column, the label changes only ~8-10 times -> run-length
// accumulate in registers, one packed u64 LDS atomic per run.
// Fields: [42..63]=cnt, [21..41]=sum_y, [0..20]=sum_x (region sums < 2^21,
// all integers < 2^22 exact in f32 -> division bitwise matches JAX).
// ---------------------------------------------------------------------------
__global__ __launch_bounds__(256) void label_kernel(const int* __restrict__ paths,
                                                    float* __restrict__ out) {
    int b = blockIdx.x;
    __shared__ int vp[NSEAM][HH];   // [seam][row] -> column
    __shared__ int hp[NSEAM][WW];   // [seam][col] -> row
    __shared__ unsigned long long acc[KK];

    const int* pb = paths + (size_t)b * 14 * HH;
    for (int i = threadIdx.x; i < NSEAM * HH; i += blockDim.x) {
        vp[i / HH][i % HH] = pb[i];
        hp[i / WW][i % WW] = pb[NSEAM * HH + i];
    }
    if (threadIdx.x < KK) acc[threadIdx.x] = 0ull;
    __syncthreads();

    const int x = threadIdx.x;
    if (x < WW) {
        int hx[NSEAM];
#pragma unroll
        for (int q = 0; q < NSEAM; ++q) hx[q] = hp[q][x];

        float* mb = out + (size_t)BB * KK * 2 + (size_t)b * HH * WW;
        int cur = -1, y0 = 0;
        for (int y = 0; y < HH; ++y) {
            int vl = 0, hl = 0;
#pragma unroll
            for (int q = 0; q < NSEAM; ++q) {
                vl += (vp[q][y] <= x) ? 1 : 0;
                hl += (hx[q] <= y) ? 1 : 0;
            }
            int lab = vl + 8 * hl;
            mb[y * WW + x] = (float)lab;
            if (lab != cur) {
                if (cur >= 0) {
                    unsigned cnt = (unsigned)(y - y0);
                    unsigned sy  = (unsigned)((y0 + y - 1) * (y - y0) / 2);
                    unsigned sx  = (unsigned)x * cnt;
                    atomicAdd(&acc[cur], ((unsigned long long)cnt << 42) |
                                         ((unsigned long long)sy << 21) |
                                         (unsigned long long)sx);
                }
                cur = lab; y0 = y;
            }
        }
        {
            unsigned cnt = (unsigned)(HH - y0);
            unsigned sy  = (unsigned)((y0 + HH - 1) * (HH - y0) / 2);
            unsigned sx  = (unsigned)x * cnt;
            atomicAdd(&acc[cur], ((unsigned long long)cnt << 42) |
                                 ((unsigned long long)sy << 21) |
                                 (unsigned long long)sx);
        }
    }
    __syncthreads();

    if (threadIdx.x < KK) {
        unsigned long long sv = acc[threadIdx.x];
        float cnt = (float)(unsigned)(sv >> 42);
        float sy  = (float)(unsigned)((sv >> 21) & 0x1FFFFFu);
        float sx  = (float)(unsigned)(sv & 0x1FFFFFu);
        float* cb = out + (size_t)b * KK * 2;
        cb[threadIdx.x * 2 + 0] = sy / cnt;
        cb[threadIdx.x * 2 + 1] = sx / cnt;
    }
}

extern "C" void kernel_launch(void* const* d_in, const int* in_sizes, int n_in,
                              void* d_out, int out_size, void* d_ws, size_t ws_size,
                              hipStream_t stream) {
    const float* g = (const float*)d_in[1];
    float* out = (float*)d_out;
    int* paths = (int*)d_ws;    // 256*14*224*4 = 3,211,264 bytes

    dp_kernel<<<(BB * 14) / 16, 256, 0, stream>>>(g, paths);
    label_kernel<<<BB, 256, 0, stream>>>(paths, out);
}

// Round 3
// 59.486 us; speedup vs baseline: 3.3436x; 1.4687x over previous
//
#include <hip/hip_runtime.h>
#include <stdint.h>

#define HH 224
#define WW 224
#define NSEAM 7
#define BWIDTH 5
#define NP 11
#define BB 256
#define KK 64
#define YCH 4
#define YROWS (HH / YCH)

// DPP helpers (ctrl must be literal): row_shr:1=0x111 (dst[i]=src[i-1]),
// row_shl:1=0x101 (dst[i]=src[i+1]), row_ror:N=0x120+N. Rows = 16 lanes.
#define DPPF_OLD(old, src, ctrl) \
    __int_as_float(__builtin_amdgcn_update_dpp(__float_as_int(old), __float_as_int(src), ctrl, 0xF, 0xF, false))
#define DPPF_Z(src, ctrl) \
    __int_as_float(__builtin_amdgcn_update_dpp(0, __float_as_int(src), ctrl, 0xF, 0xF, true))
#define DPPI_Z(src, ctrl) \
    __builtin_amdgcn_update_dpp(0, (int)(src), ctrl, 0xF, 0xF, true)

// ---------------------------------------------------------------------------
// Kernel 1: seam DP, 16 lanes per DP (lane j = band position j, 11 active).
// 3584 DPs -> 224 blocks x 256 threads. Depth-2 global prefetch (3 buffers)
// to cover ~900cy HBM miss latency. Also zeroes the centroid accumulators.
// Exact reference semantics: candidates [jm, j, jp], strict-< first-min,
// cost = best - g, final argmin first-min, backtrack via 2-bit codes.
// ---------------------------------------------------------------------------
__global__ __launch_bounds__(256) void dp_kernel(const float* __restrict__ g,
                                                 int* __restrict__ paths,
                                                 unsigned long long* __restrict__ gacc) {
    __shared__ uint32_t ch[16][226];   // packed 2-bit sels, 11 lanes per word
    __shared__ int      pth[16][226];  // backtracked path positions

    {   // zero global centroid accumulators (label kernel runs after us)
        int tid = blockIdx.x * 256 + threadIdx.x;
        if (tid < BB * KK) gacc[tid] = 0ull;
    }

    const int j   = threadIdx.x & 15;
    const int grp = threadIdx.x >> 4;
    const int gid = blockIdx.x * 16 + grp;      // (b, dir, seam)
    const int b   = gid / 14;
    const int s   = gid % 14;
    const int dir = s / 7;
    const int p   = s % 7;
    const int band0 = 28 * (p + 1) - BWIDTH;
    const int rs = (dir == 0) ? WW : 1;         // step-axis stride
    const int cs = (dir == 0) ? 1 : WW;         // band-axis stride
    const int jc = (j > 10) ? 10 : j;           // clamp junk lanes' loads
    const float* gptr = g + (size_t)b * HH * WW + (size_t)(band0 + jc) * cs;

    float gbuf[3][16];
    float cost = 0.0f;

#define LOADC(c)                                                            \
    _Pragma("unroll")                                                       \
    for (int rr = 0; rr < 16; ++rr) gbuf[(c) % 3][rr] = gptr[((c) * 16 + rr) * rs];

#define PROCC(c)                                                            \
    _Pragma("unroll")                                                       \
    for (int rr = 0; rr < 16; ++rr) {                                       \
        if (rr == 0 && (c) == 0) {                                          \
            cost = -gbuf[0][0];                                             \
        } else {                                                            \
            float pm  = DPPF_OLD(cost, cost, 0x111); /* prev[j-1], lane0 keeps old */    \
            float ppv = DPPF_OLD(cost, cost, 0x101); /* prev[j+1], lane15 keeps old */   \
            ppv = (j >= 10) ? cost : ppv;            /* clip at j=10 */                  \
            float best = pm; int sel = (j == 0) ? 1 : 0;                    \
            if (cost < best) { best = cost; sel = 1; }                      \
            if (ppv  < best) { best = ppv;  sel = 2; }                      \
            cost = best - gbuf[(c) % 3][rr];                                \
            uint32_t u = (uint32_t)sel << (2 * j);                          \
            u |= (uint32_t)DPPI_Z(u, 0x128);                                \
            u |= (uint32_t)DPPI_Z(u, 0x124);                                \
            u |= (uint32_t)DPPI_Z(u, 0x122);                                \
            u |= (uint32_t)DPPI_Z(u, 0x121);                                \
            if (j == 0) ch[grp][(c) * 16 + rr] = u;                         \
        }                                                                   \
    }

    LOADC(0);
    LOADC(1);
#pragma unroll
    for (int c = 0; c < 14; ++c) {
        if (c + 2 < 14) LOADC(c + 2);
        PROCC(c);
    }

    // final argmin across 11 lanes, first-min tie-break == lexicographic min
    float rc = (j <= 10) ? cost : INFINITY;
    int   ri = (j <= 10) ? j : 15;
#define REDSTEP(ctrl)                                                        \
    {                                                                        \
        float oc = DPPF_Z(rc, ctrl);                                         \
        int   oi = DPPI_Z(ri, ctrl);                                         \
        bool t = (oc < rc) || (oc == rc && oi < ri);                         \
        rc = t ? oc : rc; ri = t ? oi : ri;                                  \
    }
    REDSTEP(0x128) REDSTEP(0x124) REDSTEP(0x122) REDSTEP(0x121)

    int pos = ri;
    if (j == 0) pth[grp][HH - 1] = band0 + pos;

    // backtrack: uniform (broadcast) LDS reads issued ahead; chain ~3 VALU/row
    for (int c = 13; c >= 0; --c) {
        uint32_t w[16];
#pragma unroll
        for (int rr = 0; rr < 16; ++rr) w[rr] = ch[grp][c * 16 + rr];
#pragma unroll
        for (int rr = 15; rr >= 0; --rr) {
            int r = c * 16 + rr;
            if (r >= 1) {
                int sel = (int)((w[rr] >> (2 * pos)) & 3u);
                pos += sel - 1;
                if (j == 0) pth[grp][r - 1] = band0 + pos;
            }
        }
    }

    int* op = paths + (size_t)gid * HH;
#pragma unroll
    for (int c = 0; c < 14; ++c) op[c * 16 + j] = pth[grp][c * 16 + j];

#undef LOADC
#undef PROCC
#undef REDSTEP
}

// ---------------------------------------------------------------------------
// Kernel 2: labels + centroid partials. Grid = B*4 (4 y-chunks per image),
// 4 waves/SIMD occupancy. Thread = column; walks 56 rows; mask stores stay
// coalesced (lane = x). Run-length flush -> packed u64 LDS atomic per run;
// block partials -> global atomicAdd. Fields: [42..63]=cnt, [21..41]=sum_y,
// [0..20]=sum_x; per-region totals < field capacity (regions <= ~38x38,
// sums <= ~322K < 2^21), so u64 adds never carry across fields and all
// values are integers < 2^22, exact in f32 -> division matches JAX bitwise.
// ---------------------------------------------------------------------------
__global__ __launch_bounds__(256) void label_kernel(const int* __restrict__ paths,
                                                    float* __restrict__ out,
                                                    unsigned long long* __restrict__ gacc) {
    const int b  = blockIdx.x >> 2;
    const int y0 = (blockIdx.x & 3) * YROWS;
    const int y1 = y0 + YROWS;

    __shared__ int vpc[NSEAM][YROWS];
    __shared__ unsigned long long acc[KK];

    const int* pb = paths + (size_t)b * 14 * HH;
    for (int i = threadIdx.x; i < NSEAM * YROWS; i += 256) {
        int q = i / YROWS, r = i - q * YROWS;
        vpc[q][r] = pb[q * HH + y0 + r];
    }
    if (threadIdx.x < KK) acc[threadIdx.x] = 0ull;
    __syncthreads();

    const int x = threadIdx.x;
    if (x < WW) {
        int hx[NSEAM];
#pragma unroll
        for (int q = 0; q < NSEAM; ++q) hx[q] = pb[(NSEAM + q) * HH + x];

        float* mb = out + (size_t)BB * KK * 2 + (size_t)b * HH * WW;
        int cur = -1, ys = y0;
        for (int y = y0; y < y1; ++y) {
            int vl = 0, hl = 0;
#pragma unroll
            for (int q = 0; q < NSEAM; ++q) {
                vl += (vpc[q][y - y0] <= x) ? 1 : 0;
                hl += (hx[q] <= y) ? 1 : 0;
            }
            int lab = vl + 8 * hl;
            mb[y * WW + x] = (float)lab;
            if (lab != cur) {
                if (cur >= 0) {
                    unsigned cnt = (unsigned)(y - ys);
                    unsigned sy  = (unsigned)((ys + y - 1) * (y - ys) / 2);
                    unsigned sx  = (unsigned)x * cnt;
                    atomicAdd(&acc[cur], ((unsigned long long)cnt << 42) |
                                         ((unsigned long long)sy << 21) |
                                         (unsigned long long)sx);
                }
                cur = lab; ys = y;
            }
        }
        {
            unsigned cnt = (unsigned)(y1 - ys);
            unsigned sy  = (unsigned)((ys + y1 - 1) * (y1 - ys) / 2);
            unsigned sx  = (unsigned)x * cnt;
            atomicAdd(&acc[cur], ((unsigned long long)cnt << 42) |
                                 ((unsigned long long)sy << 21) |
                                 (unsigned long long)sx);
        }
    }
    __syncthreads();

    if (threadIdx.x < KK) {
        unsigned long long v = acc[threadIdx.x];
        if (v) atomicAdd(&gacc[(size_t)b * KK + threadIdx.x], v);
    }
}

// ---------------------------------------------------------------------------
// Kernel 3: finalize centroids. 16384 regions; unpack, divide, float2 store.
// ---------------------------------------------------------------------------
__global__ __launch_bounds__(256) void finalize_kernel(const unsigned long long* __restrict__ gacc,
                                                       float* __restrict__ out) {
    int i = blockIdx.x * 256 + threadIdx.x;    // < BB*KK
    unsigned long long sv = gacc[i];
    float cnt = (float)(unsigned)(sv >> 42);
    float sy  = (float)(unsigned)((sv >> 21) & 0x1FFFFFu);
    float sx  = (float)(unsigned)(sv & 0x1FFFFFu);
    float c = fmaxf(cnt, 1e-6f);
    float2 r; r.x = sy / c; r.y = sx / c;
    *reinterpret_cast<float2*>(out + (size_t)i * 2) = r;
}

extern "C" void kernel_launch(void* const* d_in, const int* in_sizes, int n_in,
                              void* d_out, int out_size, void* d_ws, size_t ws_size,
                              hipStream_t stream) {
    const float* g = (const float*)d_in[1];
    float* out = (float*)d_out;
    int* paths = (int*)d_ws;                                   // 3,211,264 B
    unsigned long long* gacc =
        (unsigned long long*)((char*)d_ws + (size_t)BB * 14 * HH * 4);  // 128 KiB

    dp_kernel<<<(BB * 14) / 16, 256, 0, stream>>>(g, paths, gacc);
    label_kernel<<<BB * YCH, 256, 0, stream>>>(paths, out, gacc);
    finalize_kernel<<<(BB * KK) / 256, 256, 0, stream>>>(gacc, out);
}